// Round 8
// baseline (2347.168 us; speedup 1.0000x reference)
//
#include <hip/hip_runtime.h>
#include <math.h>

#define S_LEN 2048
#define DMODEL 2048
#define NHQ 16
#define NHK 4
#define HDIM 128
#define PDIM 8192
#define VOCAB 32000
#define NQKV 3072          // D + 2*HK*HD
#define EPSI 1e-5f

typedef unsigned short u16;
typedef unsigned int u32;
typedef __bf16 bf16x8 __attribute__((ext_vector_type(8)));
typedef float f32x4 __attribute__((ext_vector_type(4)));

__device__ __forceinline__ u16 f2bf(float f){
  u32 u = __builtin_bit_cast(u32, f);
  u += 0x7fffu + ((u >> 16) & 1u);   // RNE
  return (u16)(u >> 16);
}
__device__ __forceinline__ float bf2f(u16 h){
  u32 u = ((u32)h) << 16;
  return __builtin_bit_cast(float, u);
}
__device__ __forceinline__ bf16x8 ld8(const u16* p){
  return __builtin_bit_cast(bf16x8, *(const uint4*)p);
}
__device__ __forceinline__ f32x4 mfma16(bf16x8 a, bf16x8 b, f32x4 c){
  return __builtin_amdgcn_mfma_f32_16x16x32_bf16(a, b, c, 0, 0, 0);
}

#define GLOAD_LDS16(gp, lp) __builtin_amdgcn_global_load_lds( \
    (__attribute__((address_space(1))) void*)(gp), \
    (__attribute__((address_space(3))) void*)(lp), 16, 0, 0)

// Swizzled LDS tile layout: [Rows][32k] bf16 stored as row-PAIRS; line Rp=R>>1
// holds rows {2Rp,2Rp+1} x 32 k = 128 B = 8 slots of 16 B, slot XOR (Rp&7).
// gload_lds dest LINEAR; permutation applied to per-lane GLOBAL source.
// 0 bank conflicts measured (R3-R7).
__device__ __forceinline__ bf16x8 lds_frag(const u16* Lb, int R, int g){
  const int Rp = R >> 1;
  const int s8 = (((R & 1) << 2) | g) ^ (Rp & 7);
  return ld8(Lb + Rp * 64 + s8 * 8);
}
__device__ __forceinline__ void stage_sw(const u16* base, long row0, int K, int kt,
                                         int q, u16* Ldst_waveuniform){
  const int Rp = q >> 3;
  const int u = (q & 7) ^ (Rp & 7);
  const int R = (Rp << 1) | (u >> 2);
  const u16* gp = base + (row0 + R) * (long)K + kt + ((u & 3) << 3);
  GLOAD_LDS16(gp, Ldst_waveuniform);
}

// XCD-contiguous, bm-grouped block mapping for the 128^2 GEMM.
__device__ __forceinline__ void map_bmn(int id0, int nwg, int nbn, int G,
                                        int& bm, int& bn){
  const int cpx = nwg >> 3;               // nwg % 8 == 0 at all call sites
  const int id = (id0 & 7) * cpx + (id0 >> 3);
  const int bmi = id % G;
  const int r2 = id / G;
  bn = r2 % nbn;
  bm = (r2 / nbn) * G + bmi;
}

// -------------------- embed gather --------------------
__global__ void k_embed(const int* __restrict__ tok, const float* __restrict__ emb,
                        float* __restrict__ x){
  const int s = blockIdx.x, t = threadIdx.x;
  const long r = tok[s];
  const float4* src = (const float4*)(emb + r * DMODEL);
  float4* dst = (float4*)(x + (long)s * DMODEL);
  dst[t] = src[t];
  dst[t + 256] = src[t + 256];
}

// -------------------- RMSNorm: fp32 in -> bf16 out --------------------
__global__ void k_rmsnorm(const float* __restrict__ x, const float* __restrict__ w,
                          u16* __restrict__ out){
  const int s = blockIdx.x, t = threadIdx.x;
  const float4* xr = (const float4*)(x + (long)s * DMODEL);
  const float4 a = xr[t], b = xr[t + 256];
  float ss = a.x*a.x + a.y*a.y + a.z*a.z + a.w*a.w
           + b.x*b.x + b.y*b.y + b.z*b.z + b.w*b.w;
  #pragma unroll
  for (int off = 32; off > 0; off >>= 1) ss += __shfl_down(ss, off, 64);
  __shared__ float part[4];
  if ((t & 63) == 0) part[t >> 6] = ss;
  __syncthreads();
  const float r = rsqrtf((part[0] + part[1] + part[2] + part[3]) * (1.f / 2048.f) + EPSI);
  const float4* wr = (const float4*)w;
  const float4 wa = wr[t], wb = wr[t + 256];
  uint2 ua, ub;
  ua.x = (u32)f2bf(a.x*r*wa.x) | ((u32)f2bf(a.y*r*wa.y) << 16);
  ua.y = (u32)f2bf(a.z*r*wa.z) | ((u32)f2bf(a.w*r*wa.w) << 16);
  ub.x = (u32)f2bf(b.x*r*wb.x) | ((u32)f2bf(b.y*r*wb.y) << 16);
  ub.y = (u32)f2bf(b.z*r*wb.z) | ((u32)f2bf(b.w*r*wb.w) << 16);
  *(uint2*)(out + (long)s * DMODEL + 4 * t) = ua;
  *(uint2*)(out + (long)s * DMODEL + 1024 + 4 * t) = ub;
}

// -------------------- weight convert + transpose: W f32[K][N] -> Wt bf16[N][K] ---
__global__ __launch_bounds__(256) void k_convT(const float* __restrict__ W,
                                               u16* __restrict__ Wt, int N, int K){
  const int n0 = blockIdx.x * 64, k0 = blockIdx.y * 64;
  const int t = threadIdx.x;
  __shared__ u16 T[64][72];    // [n][k], padded
  const int r = t >> 4, c = (t & 15) << 2;
  #pragma unroll
  for (int p = 0; p < 4; ++p){
    const int k = p * 16 + r;
    const float4 v = *(const float4*)(W + (long)(k0 + k) * N + n0 + c);
    T[c + 0][k] = f2bf(v.x);
    T[c + 1][k] = f2bf(v.y);
    T[c + 2][k] = f2bf(v.z);
    T[c + 3][k] = f2bf(v.w);
  }
  __syncthreads();
  const int nr = t >> 3, kc = (t & 7) << 3;
  #pragma unroll
  for (int p = 0; p < 2; ++p){
    const int n = p * 32 + nr;
    *(uint4*)(Wt + (long)(n0 + n) * K + k0 + kc) = *(const uint4*)(&T[n][kc]);
  }
}

// -------------------- V transpose: qkv V-part [S][4][128] -> vT [4][128][S] ------
__global__ __launch_bounds__(256) void k_transV(const u16* __restrict__ qkv,
                                                u16* __restrict__ vT){
  const int s0 = blockIdx.x * 64, d0 = blockIdx.y * 64, kh = blockIdx.z;
  const int t = threadIdx.x;
  __shared__ u16 T[64][72];   // [d][s]
  #pragma unroll
  for (int p = 0; p < 4; ++p){
    const int s = p * 16 + (t >> 4);
    const int c = (t & 15) * 4;
    const uint2 v = *(const uint2*)(qkv + (long)(s0 + s) * NQKV + DMODEL + 512 + kh * HDIM + d0 + c);
    T[c + 0][s] = (u16)(v.x);
    T[c + 1][s] = (u16)(v.x >> 16);
    T[c + 2][s] = (u16)(v.y);
    T[c + 3][s] = (u16)(v.y >> 16);
  }
  __syncthreads();
  #pragma unroll
  for (int p = 0; p < 2; ++p){
    const int d = p * 32 + (t >> 3);
    *(uint4*)(vT + ((long)kh * HDIM + d0 + d) * S_LEN + s0 + (t & 7) * 8) =
        *(const uint4*)(&T[d][(t & 7) * 8]);
  }
}

// -------------------- GEMM 128x128 (m97-structure, swizzled LDS, 1D mapped grid) --
template<int OUT_BF16, int RES>
__global__ __launch_bounds__(256) void k_gemm(const u16* __restrict__ A, const u16* __restrict__ Bt,
                                              void* C, const float* Rs,
                                              int M, int N, int K, int nbn, int G){
  int bm, bn;
  map_bmn(blockIdx.x, gridDim.x, nbn, G, bm, bn);
  const int t = threadIdx.x;
  const int w = t >> 6, lane = t & 63, l15 = lane & 15, g = lane >> 4;
  const int wr = w >> 1, wc = w & 1;
  __shared__ u16 As[4096];
  __shared__ u16 Bs[4096];
  f32x4 acc[4][4] = {};
  const long arow = (long)bm * 128;
  const long brow = (long)bn * 128;
  for (int kt = 0; kt < K; kt += 32){
    __syncthreads();
    #pragma unroll
    for (int c = 0; c < 2; ++c){
      const int q0 = ((w << 1) | c) << 6;
      const int q  = q0 | lane;
      stage_sw(A,  arow, K, kt, q, As + q0 * 8);
      stage_sw(Bt, brow, K, kt, q, Bs + q0 * 8);
    }
    __syncthreads();
    bf16x8 af[4], bfr[4];
    #pragma unroll
    for (int i = 0; i < 4; ++i)
      af[i] = lds_frag(As, wr * 64 + i * 16 + l15, g);
    #pragma unroll
    for (int i = 0; i < 4; ++i)
      bfr[i] = lds_frag(Bs, wc * 64 + i * 16 + l15, g);
    #pragma unroll
    for (int mi = 0; mi < 4; ++mi)
      #pragma unroll
      for (int ni = 0; ni < 4; ++ni)
        acc[mi][ni] = mfma16(af[mi], bfr[ni], acc[mi][ni]);
  }
  const int row0 = bm * 128 + wr * 64, col0 = bn * 128 + wc * 64;
  #pragma unroll
  for (int mi = 0; mi < 4; ++mi){
    #pragma unroll
    for (int ni = 0; ni < 4; ++ni){
      #pragma unroll
      for (int r = 0; r < 4; ++r){
        const long ri = row0 + mi * 16 + g * 4 + r;
        const long ci = col0 + ni * 16 + l15;
        float v = acc[mi][ni][r];
        if (RES) v += Rs[ri * N + ci];
        if (OUT_BF16) ((u16*)C)[ri * N + ci] = f2bf(v);
        else          ((float*)C)[ri * N + ci] = v;
      }
    }
  }
}

// -------------------- GEMM 256x128, direct-B, 2 blocks/CU ------------------------
// K fixed = 2048. 8 waves: wr=w>>1 (64 rows), wc=w&1 (64 cols); per-wave 64x64.
// A: gload_lds staged, 4 slots x 16 KB = 64 KB LDS (2 blocks/CU). B: fragments
// loaded DIRECTLY global->VGPR (B^T[n][k]: 16 rows x full 64B line per frag set),
// 1-tile register double-buffer, no barrier coupling. Per tile: [issue B(t+1) x4,
// A-DMA(t+3) x2] -> vmcnt(8) -> barrier -> 4 ds_read frags -> 16 MFMA -> barrier.
// vmcnt(8) ledger: newest 8 = B(t+1)4 + A(t+3)2 + A(t+2)2 => A(t),A(t+1),B(t)
// landed; at tail (t=NT-1) newest 8 = B(NT-2)4+B(NT-1)4 => A(NT-1) landed.
// WAR: A-DMA(t+3) hits slot (t-1)&3 whose frag reads completed before tile
// t-1's end barrier (register dependency drains ds_reads before MFMA issue).
template<int OUT_BF16>
__global__ __launch_bounds__(512, 2) void k_gemmD(const u16* __restrict__ A,
                                                  const u16* __restrict__ Bt,
                                                  void* C, int M, int N){
  const int KK = 2048;
  __shared__ u16 As[4][8192];                // 4 slots x 16 KB
  const int t = threadIdx.x;
  const int w = t >> 6, lane = t & 63, l15 = lane & 15, g = lane >> 4;
  const int wr = w >> 1, wc = w & 1;
  const int bm = blockIdx.x & 7;             // nbm == 8 (M == 2048)
  const int bn = blockIdx.x >> 3;
  const int NT = KK / 32;                    // 64, even

  // hoisted A staging addresses (chunks q=t -> rows 0..127, q=t+512 -> +128)
  const int Rp0 = t >> 3;
  const int u0  = (t & 7) ^ (Rp0 & 7);
  const int R0  = (Rp0 << 1) | (u0 >> 2);
  const u16* pA0 = A + ((long)bm * 256 + R0) * KK + ((u0 & 3) << 3);
  const u16* pA1 = pA0 + 128 * KK;
  const int w0 = (t & ~63) * 8;              // wave-uniform LDS chunk base (u16)

  // direct-B base: lane reads row (bn*128 + wc*64 + ni*16 + l15), k byte g*16
  const u16* pB = Bt + ((long)bn * 128 + wc * 64 + l15) * KK + g * 8;

  auto stageA = [&](int slot){
    GLOAD_LDS16(pA0, As[slot] + w0);
    GLOAD_LDS16(pA1, As[slot] + 4096 + w0);
    pA0 += 32; pA1 += 32;
  };

  // prologue: A tiles 0..2; B tile 0
  stageA(0); stageA(1); stageA(2);
  bf16x8 b0[4], b1[4];
  #pragma unroll
  for (int ni = 0; ni < 4; ++ni) b0[ni] = ld8(pB + ni * 16 * KK);
  pB += 32;

  f32x4 acc[4][4] = {};

  #define TILE_STEP(tt, bc, bx)                                               \
  {                                                                           \
    if ((tt) + 1 < NT){                                                       \
      _Pragma("unroll")                                                       \
      for (int ni = 0; ni < 4; ++ni) bx[ni] = ld8(pB + ni * 16 * KK);         \
      pB += 32;                                                               \
    }                                                                         \
    if ((tt) + 3 < NT) stageA(((tt) + 3) & 3);                                \
    asm volatile("s_waitcnt vmcnt(8)" ::: "memory");                          \
    __builtin_amdgcn_s_barrier();                                             \
    bf16x8 af[4];                                                             \
    _Pragma("unroll")                                                         \
    for (int mi = 0; mi < 4; ++mi)                                            \
      af[mi] = lds_frag(As[(tt) & 3], wr * 64 + mi * 16 + l15, g);            \
    __builtin_amdgcn_s_setprio(1);                                            \
    _Pragma("unroll")                                                         \
    for (int mi = 0; mi < 4; ++mi)                                            \
      _Pragma("unroll")                                                       \
      for (int ni = 0; ni < 4; ++ni)                                          \
        acc[mi][ni] = mfma16(af[mi], bc[ni], acc[mi][ni]);                    \
    __builtin_amdgcn_s_setprio(0);                                            \
    __builtin_amdgcn_s_barrier();                                             \
  }

  for (int tt = 0; tt < NT; tt += 2){
    TILE_STEP(tt,     b0, b1);
    TILE_STEP(tt + 1, b1, b0);
  }
  #undef TILE_STEP

  // ---- epilogue ----
  const int row0 = bm * 256 + wr * 64, col0 = bn * 128 + wc * 64;
  #pragma unroll
  for (int mi = 0; mi < 4; ++mi){
    #pragma unroll
    for (int ni = 0; ni < 4; ++ni){
      #pragma unroll
      for (int r = 0; r < 4; ++r){
        const long ri = row0 + mi * 16 + g * 4 + r;
        const long ci = col0 + ni * 16 + l15;
        const float v = acc[mi][ni][r];
        if (OUT_BF16) ((u16*)C)[ri * N + ci] = f2bf(v);
        else          ((float*)C)[ri * N + ci] = v;
      }
    }
  }
}

// -------------------- RoPE in-place on bf16 qkv --------------------
__global__ void k_rope(u16* __restrict__ qkv){
  const int idx = blockIdx.x * 256 + threadIdx.x;   // S * 20 * 64
  const int i = idx & 63;
  const int head = (idx >> 6) % 20;
  const int s = idx / (64 * 20);
  const long base = (long)s * NQKV + (head < NHQ ? head * HDIM : DMODEL + (head - NHQ) * HDIM);
  u32* p = (u32*)(qkv + base + 2 * i);
  const u32 v = *p;
  const float x0 = bf2f((u16)(v & 0xffffu)), x1 = bf2f((u16)(v >> 16));
  const float ang = (float)s * exp2f(-0.29580575889569023f * (float)i);
  float sn, cs;
  sincosf(ang, &sn, &cs);
  const float y0 = x0 * cs - x1 * sn;
  const float y1 = x0 * sn + x1 * cs;
  *p = (u32)f2bf(y0) | ((u32)f2bf(y1) << 16);
}

// -------------------- Flash attention (causal, GQA), gload_lds staged ------------
// 1D grid of 512: xcd = id&7 -> kh = xcd>>1 (KV head L2-pinned per XCD);
// qb DESCENDS with id so longest blocks dispatch first (LPT balance).
__global__ __launch_bounds__(256) void k_attn(const u16* __restrict__ qkv,
                                              const u16* __restrict__ vT,
                                              u16* __restrict__ o){
  const int id = blockIdx.x;
  const int xcd = id & 7, j = id >> 3;
  const int kh = xcd >> 1;
  const int h  = (kh << 2) + ((xcd & 1) << 1) + (j & 1);
  const int qb = 31 - (j >> 1);
  const int t = threadIdx.x, w = t >> 6, lane = t & 63, l15 = lane & 15, g = lane >> 4;
  __shared__ u16 Ks[2][8192];
  __shared__ u16 Vs[2][8192];
  __shared__ u16 Ps[4][16 * 72];
  const int q0 = qb * 64 + w * 16;
  bf16x8 aq[4];
  #pragma unroll
  for (int d0 = 0; d0 < 4; ++d0)
    aq[d0] = ld8(qkv + (long)(q0 + l15) * NQKV + h * HDIM + d0 * 32 + g * 8);
  f32x4 acc_o[8] = {};
  float mst[4], lst[4];
  #pragma unroll
  for (int r = 0; r < 4; ++r){ mst[r] = -1e30f; lst[r] = 0.f; }
  const float scale = 0.08838834764831843f;

  auto stageK = [&](int kt, int b){
    #pragma unroll
    for (int p = 0; p < 4; ++p){
      const int q = p * 256 + t;
      const int r = q >> 4, u = q & 15;
      const u16* gp = qkv + (long)(kt * 64 + r) * NQKV + DMODEL + kh * HDIM + ((u ^ (r & 15)) << 3);
      GLOAD_LDS16(gp, Ks[b] + (p * 256 + (t & ~63)) * 8);
    }
  };
  auto stageV = [&](int kt, int b){
    #pragma unroll
    for (int p = 0; p < 4; ++p){
      const int q = p * 256 + t;
      const int r = q >> 3, u = q & 7;
      const u16* gp = vT + ((long)kh * HDIM + r) * S_LEN + kt * 64 + ((u ^ (r & 7)) << 3);
      GLOAD_LDS16(gp, Vs[b] + (p * 256 + (t & ~63)) * 8);
    }
  };

  const int nkt = qb + 1;
  stageK(0, 0); stageV(0, 0);
  for (int kt = 0; kt < nkt; ++kt){
    const int kv0 = kt << 6;
    __builtin_amdgcn_s_barrier();            // (a) prev reads drained -> DMA may overwrite
    if (kt + 1 < nkt){
      stageK(kt + 1, (kt + 1) & 1);
      stageV(kt + 1, (kt + 1) & 1);
      asm volatile("s_waitcnt vmcnt(8)" ::: "memory");
    } else {
      asm volatile("s_waitcnt vmcnt(0)" ::: "memory");
    }
    __builtin_amdgcn_s_barrier();            // (b) tile kt globally visible
    const u16* K_ = Ks[kt & 1];
    const u16* V_ = Vs[kt & 1];
    // ---- S = Q K^T ----
    f32x4 sacc[4] = {};
    #pragma unroll
    for (int d0 = 0; d0 < 4; ++d0){
      #pragma unroll
      for (int j2 = 0; j2 < 4; ++j2){
        const bf16x8 bk = ld8(K_ + (j2 * 16 + l15) * 128 + ((((d0 << 2) | g) ^ l15) << 3));
        sacc[j2] = mfma16(aq[d0], bk, sacc[j2]);
      }
    }
    // ---- mask + online softmax (rows in 16-lane groups) ----
    float p[4][4], scl[4];
    #pragma unroll
    for (int r = 0; r < 4; ++r){
      const int qrow = q0 + g * 4 + r;
      float mx = -1e30f;
      #pragma unroll
      for (int j2 = 0; j2 < 4; ++j2){
        float sv = sacc[j2][r] * scale;
        sv = (kv0 + j2 * 16 + l15 <= qrow) ? sv : -1e30f;
        p[j2][r] = sv;
        mx = fmaxf(mx, sv);
      }
      #pragma unroll
      for (int off = 1; off < 16; off <<= 1) mx = fmaxf(mx, __shfl_xor(mx, off, 64));
      const float mnew = fmaxf(mst[r], mx);
      scl[r] = __expf(mst[r] - mnew);
      float rs = 0.f;
      #pragma unroll
      for (int j2 = 0; j2 < 4; ++j2){ p[j2][r] = __expf(p[j2][r] - mnew); rs += p[j2][r]; }
      #pragma unroll
      for (int off = 1; off < 16; off <<= 1) rs += __shfl_xor(rs, off, 64);
      lst[r] = lst[r] * scl[r] + rs;
      mst[r] = mnew;
    }
    #pragma unroll
    for (int n = 0; n < 8; ++n)
      #pragma unroll
      for (int r = 0; r < 4; ++r)
        acc_o[n][r] *= scl[r];
    // ---- P -> LDS (per-wave), then PV ----
    #pragma unroll
    for (int j2 = 0; j2 < 4; ++j2)
      #pragma unroll
      for (int r = 0; r < 4; ++r)
        Ps[w][(g * 4 + r) * 72 + j2 * 16 + l15] = f2bf(p[j2][r]);
    #pragma unroll
    for (int kk = 0; kk < 2; ++kk){
      const bf16x8 pa = ld8(Ps[w] + l15 * 72 + kk * 32 + g * 8);
      #pragma unroll
      for (int n = 0; n < 8; ++n){
        const int row = n * 16 + l15;
        const bf16x8 bv = ld8(V_ + row * 64 + ((((kk << 2) | g) ^ (l15 & 7)) << 3));
        acc_o[n] = mfma16(pa, bv, acc_o[n]);
      }
    }
    asm volatile("s_waitcnt lgkmcnt(0)" ::: "memory");   // drain my LDS reads (WAR)
  }
  #pragma unroll
  for (int n = 0; n < 8; ++n){
    #pragma unroll
    for (int r = 0; r < 4; ++r){
      const float ov = acc_o[n][r] / lst[r];
      o[(long)(q0 + g * 4 + r) * DMODEL + h * HDIM + n * 16 + l15] = f2bf(ov);
    }
  }
}

// -------------------- SwiGLU: silu(gate)*up --------------------
__global__ void k_swiglu(const u16* __restrict__ gu, u16* __restrict__ out){
  const long idx = ((long)blockIdx.x * 256 + threadIdx.x) * 8;
  const long s = idx >> 13;
  const int j = (int)(idx & 8191);
  const u16* gp = gu + s * 16384 + j;
  const uint4 gv = *(const uint4*)gp;
  const uint4 uv = *(const uint4*)(gp + PDIM);
  const u32 gw[4] = {gv.x, gv.y, gv.z, gv.w};
  const u32 uw[4] = {uv.x, uv.y, uv.z, uv.w};
  u32 ow[4];
  #pragma unroll
  for (int k = 0; k < 4; ++k){
    const float g0 = bf2f((u16)(gw[k] & 0xffffu)), g1 = bf2f((u16)(gw[k] >> 16));
    const float u0 = bf2f((u16)(uw[k] & 0xffffu)), u1 = bf2f((u16)(uw[k] >> 16));
    const float s0 = g0 / (1.f + __expf(-g0)) * u0;
    const float s1 = g1 / (1.f + __expf(-g1)) * u1;
    ow[k] = (u32)f2bf(s0) | ((u32)f2bf(s1) << 16);
  }
  uint4 ro; ro.x = ow[0]; ro.y = ow[1]; ro.z = ow[2]; ro.w = ow[3];
  *(uint4*)(out + idx) = ro;
}

// -------------------- launch --------------------
extern "C" void kernel_launch(void* const* d_in, const int* in_sizes, int n_in,
                              void* d_out, int out_size, void* d_ws, size_t ws_size,
                              hipStream_t stream){
  const int*   tokens       = (const int*)d_in[0];
  const float* embed        = (const float*)d_in[1];
  const float* attn_norm_w  = (const float*)d_in[2];
  const float* qkv_w        = (const float*)d_in[3];
  const float* attn_out_w   = (const float*)d_in[4];
  const float* mlp_norm_w   = (const float*)d_in[5];
  const float* mlp_in_w     = (const float*)d_in[6];
  const float* mlp_out_w    = (const float*)d_in[7];
  const float* final_norm_w = (const float*)d_in[8];
  const float* lm_head_w    = (const float*)d_in[9];

  char* ws = (char*)d_ws;
  float* xf  = (float*)(ws);                    // 16.78 MB residual (fp32)
  u16* hbf   = (u16*)(ws + 16777216);           //  8.39 MB normed activations
  u16* qkvb  = (u16*)(ws + 25165824);           // 12.58 MB qkv
  u16* obf   = (u16*)(ws + 37748736);           //  8.39 MB attn out
  u16* gub   = (u16*)(ws + 46137344);           // 67.11 MB gate|up
  u16* hb2   = (u16*)(ws + 113246208);          // 33.55 MB silu(g)*u
  u16* wbuf  = (u16*)(ws + 146800640);          // 131.07 MB transposed bf16 weights
  u16* vTb   = (u16*)(ws + 277872640);          //  2.10 MB transposed V

  k_embed<<<S_LEN, 256, 0, stream>>>(tokens, embed, xf);
  for (int l = 0; l < 2; ++l){
    k_rmsnorm<<<S_LEN, 256, 0, stream>>>(xf, attn_norm_w + (long)l * DMODEL, hbf);
    k_convT<<<dim3(NQKV/64, DMODEL/64), 256, 0, stream>>>(
        qkv_w + (long)l * DMODEL * NQKV, wbuf, NQKV, DMODEL);
    k_gemm<1,0><<<(S_LEN/128) * (NQKV/128), 256, 0, stream>>>(
        hbf, wbuf, qkvb, nullptr, S_LEN, NQKV, DMODEL, NQKV/128, 4);
    k_rope<<<(S_LEN * 20 * 64) / 256, 256, 0, stream>>>(qkvb);
    k_transV<<<dim3(S_LEN/64, 2, 4), 256, 0, stream>>>(qkvb, vTb);
    k_attn<<<512, 256, 0, stream>>>(qkvb, vTb, obf);
    k_convT<<<dim3(DMODEL/64, DMODEL/64), 256, 0, stream>>>(
        attn_out_w + (long)l * DMODEL * DMODEL, wbuf, DMODEL, DMODEL);
    k_gemm<0,1><<<(S_LEN/128) * (DMODEL/128), 256, 0, stream>>>(
        obf, wbuf, xf, xf, S_LEN, DMODEL, DMODEL, DMODEL/128, 4);
    k_rmsnorm<<<S_LEN, 256, 0, stream>>>(xf, mlp_norm_w + (long)l * DMODEL, hbf);
    k_convT<<<dim3((2*PDIM)/64, DMODEL/64), 256, 0, stream>>>(
        mlp_in_w + (long)l * DMODEL * 2 * PDIM, wbuf, 2*PDIM, DMODEL);
    k_gemmD<1><<<8 * ((2*PDIM)/128), 512, 0, stream>>>(
        hbf, wbuf, gub, S_LEN, 2*PDIM);
    k_swiglu<<<(S_LEN * PDIM / 8) / 256, 256, 0, stream>>>(gub, hb2);
    k_convT<<<dim3(DMODEL/64, PDIM/64), 256, 0, stream>>>(
        mlp_out_w + (long)l * PDIM * DMODEL, wbuf, DMODEL, PDIM);
    k_gemm<0,1><<<(S_LEN/128) * (DMODEL/128), 256, 0, stream>>>(
        hb2, wbuf, xf, xf, S_LEN, DMODEL, PDIM, DMODEL/128, 2);
  }
  k_rmsnorm<<<S_LEN, 256, 0, stream>>>(xf, final_norm_w, hbf);
  k_convT<<<dim3(VOCAB/64, DMODEL/64), 256, 0, stream>>>(lm_head_w, wbuf, VOCAB, DMODEL);
  k_gemmD<0><<<8 * (VOCAB/128), 512, 0, stream>>>(
      hbf, wbuf, (float*)d_out, S_LEN, VOCAB);
}

// Round 9
// 1416.126 us; speedup vs baseline: 1.6575x; 1.6575x over previous
//
#include <hip/hip_runtime.h>
#include <math.h>

#define S_LEN 2048
#define DMODEL 2048
#define NHQ 16
#define NHK 4
#define HDIM 128
#define PDIM 8192
#define VOCAB 32000
#define NQKV 3072          // D + 2*HK*HD
#define EPSI 1e-5f

typedef unsigned short u16;
typedef unsigned int u32;
typedef __bf16 bf16x8 __attribute__((ext_vector_type(8)));
typedef float f32x4 __attribute__((ext_vector_type(4)));

__device__ __forceinline__ u16 f2bf(float f){
  u32 u = __builtin_bit_cast(u32, f);
  u += 0x7fffu + ((u >> 16) & 1u);   // RNE
  return (u16)(u >> 16);
}
__device__ __forceinline__ float bf2f(u16 h){
  u32 u = ((u32)h) << 16;
  return __builtin_bit_cast(float, u);
}
__device__ __forceinline__ bf16x8 ld8(const u16* p){
  return __builtin_bit_cast(bf16x8, *(const uint4*)p);
}
__device__ __forceinline__ f32x4 mfma16(bf16x8 a, bf16x8 b, f32x4 c){
  return __builtin_amdgcn_mfma_f32_16x16x32_bf16(a, b, c, 0, 0, 0);
}

#define GLOAD_LDS16(gp, lp) __builtin_amdgcn_global_load_lds( \
    (__attribute__((address_space(1))) void*)(gp), \
    (__attribute__((address_space(3))) void*)(lp), 16, 0, 0)

// Swizzled LDS tile layout: [Rows][32k] bf16 stored as row-PAIRS; line Rp=R>>1
// holds rows {2Rp,2Rp+1} x 32 k = 128 B = 8 slots of 16 B, slot XOR (Rp&7).
// gload_lds dest LINEAR; permutation applied to per-lane GLOBAL source.
// 0 bank conflicts measured (R3-R8).
__device__ __forceinline__ bf16x8 lds_frag(const u16* Lb, int R, int g){
  const int Rp = R >> 1;
  const int s8 = (((R & 1) << 2) | g) ^ (Rp & 7);
  return ld8(Lb + Rp * 64 + s8 * 8);
}
// kstride = row stride of the source matrix; kt = k offset within the row.
__device__ __forceinline__ void stage_sw(const u16* base, long row0, int kstride, int kt,
                                         int q, u16* Ldst_waveuniform){
  const int Rp = q >> 3;
  const int u = (q & 7) ^ (Rp & 7);
  const int R = (Rp << 1) | (u >> 2);
  const u16* gp = base + (row0 + R) * (long)kstride + kt + ((u & 3) << 3);
  GLOAD_LDS16(gp, Ldst_waveuniform);
}

// XCD-contiguous, bm-grouped block mapping for the 128^2 GEMM.
__device__ __forceinline__ void map_bmn(int id0, int nwg, int nbn, int G,
                                        int& bm, int& bn){
  const int cpx = nwg >> 3;               // nwg % 8 == 0 at all call sites
  const int id = (id0 & 7) * cpx + (id0 >> 3);
  const int bmi = id % G;
  const int r2 = id / G;
  bn = r2 % nbn;
  bm = (r2 / nbn) * G + bmi;
}

// -------------------- embed gather --------------------
__global__ void k_embed(const int* __restrict__ tok, const float* __restrict__ emb,
                        float* __restrict__ x){
  const int s = blockIdx.x, t = threadIdx.x;
  const long r = tok[s];
  const float4* src = (const float4*)(emb + r * DMODEL);
  float4* dst = (float4*)(x + (long)s * DMODEL);
  dst[t] = src[t];
  dst[t + 256] = src[t + 256];
}

// -------------------- RMSNorm: fp32 in -> bf16 out --------------------
__global__ void k_rmsnorm(const float* __restrict__ x, const float* __restrict__ w,
                          u16* __restrict__ out){
  const int s = blockIdx.x, t = threadIdx.x;
  const float4* xr = (const float4*)(x + (long)s * DMODEL);
  const float4 a = xr[t], b = xr[t + 256];
  float ss = a.x*a.x + a.y*a.y + a.z*a.z + a.w*a.w
           + b.x*b.x + b.y*b.y + b.z*b.z + b.w*b.w;
  #pragma unroll
  for (int off = 32; off > 0; off >>= 1) ss += __shfl_down(ss, off, 64);
  __shared__ float part[4];
  if ((t & 63) == 0) part[t >> 6] = ss;
  __syncthreads();
  const float r = rsqrtf((part[0] + part[1] + part[2] + part[3]) * (1.f / 2048.f) + EPSI);
  const float4* wr = (const float4*)w;
  const float4 wa = wr[t], wb = wr[t + 256];
  uint2 ua, ub;
  ua.x = (u32)f2bf(a.x*r*wa.x) | ((u32)f2bf(a.y*r*wa.y) << 16);
  ua.y = (u32)f2bf(a.z*r*wa.z) | ((u32)f2bf(a.w*r*wa.w) << 16);
  ub.x = (u32)f2bf(b.x*r*wb.x) | ((u32)f2bf(b.y*r*wb.y) << 16);
  ub.y = (u32)f2bf(b.z*r*wb.z) | ((u32)f2bf(b.w*r*wb.w) << 16);
  *(uint2*)(out + (long)s * DMODEL + 4 * t) = ua;
  *(uint2*)(out + (long)s * DMODEL + 1024 + 4 * t) = ub;
}

// -------------------- weight convert + transpose: W f32[K][N] -> Wt bf16[N][K] ---
__global__ __launch_bounds__(256) void k_convT(const float* __restrict__ W,
                                               u16* __restrict__ Wt, int N, int K){
  const int n0 = blockIdx.x * 64, k0 = blockIdx.y * 64;
  const int t = threadIdx.x;
  __shared__ u16 T[64][72];    // [n][k], padded
  const int r = t >> 4, c = (t & 15) << 2;
  #pragma unroll
  for (int p = 0; p < 4; ++p){
    const int k = p * 16 + r;
    const float4 v = *(const float4*)(W + (long)(k0 + k) * N + n0 + c);
    T[c + 0][k] = f2bf(v.x);
    T[c + 1][k] = f2bf(v.y);
    T[c + 2][k] = f2bf(v.z);
    T[c + 3][k] = f2bf(v.w);
  }
  __syncthreads();
  const int nr = t >> 3, kc = (t & 7) << 3;
  #pragma unroll
  for (int p = 0; p < 2; ++p){
    const int n = p * 32 + nr;
    *(uint4*)(Wt + (long)(n0 + n) * K + k0 + kc) = *(const uint4*)(&T[n][kc]);
  }
}

// -------------------- V transpose: qkv V-part [S][4][128] -> vT [4][128][S] ------
__global__ __launch_bounds__(256) void k_transV(const u16* __restrict__ qkv,
                                                u16* __restrict__ vT){
  const int s0 = blockIdx.x * 64, d0 = blockIdx.y * 64, kh = blockIdx.z;
  const int t = threadIdx.x;
  __shared__ u16 T[64][72];   // [d][s]
  #pragma unroll
  for (int p = 0; p < 4; ++p){
    const int s = p * 16 + (t >> 4);
    const int c = (t & 15) * 4;
    const uint2 v = *(const uint2*)(qkv + (long)(s0 + s) * NQKV + DMODEL + 512 + kh * HDIM + d0 + c);
    T[c + 0][s] = (u16)(v.x);
    T[c + 1][s] = (u16)(v.x >> 16);
    T[c + 2][s] = (u16)(v.y);
    T[c + 3][s] = (u16)(v.y >> 16);
  }
  __syncthreads();
  #pragma unroll
  for (int p = 0; p < 2; ++p){
    const int d = p * 32 + (t >> 3);
    *(uint4*)(vT + ((long)kh * HDIM + d0 + d) * S_LEN + s0 + (t & 7) * 8) =
        *(const uint4*)(&T[d][(t & 7) * 8]);
  }
}

// -------------------- GEMM 128x128 (m97-structure, swizzled LDS, 1D mapped grid) --
template<int OUT_BF16, int RES>
__global__ __launch_bounds__(256) void k_gemm(const u16* __restrict__ A, const u16* __restrict__ Bt,
                                              void* C, const float* Rs,
                                              int M, int N, int K, int nbn, int G){
  int bm, bn;
  map_bmn(blockIdx.x, gridDim.x, nbn, G, bm, bn);
  const int t = threadIdx.x;
  const int w = t >> 6, lane = t & 63, l15 = lane & 15, g = lane >> 4;
  const int wr = w >> 1, wc = w & 1;
  __shared__ u16 As[4096];
  __shared__ u16 Bs[4096];
  f32x4 acc[4][4] = {};
  const long arow = (long)bm * 128;
  const long brow = (long)bn * 128;
  for (int kt = 0; kt < K; kt += 32){
    __syncthreads();
    #pragma unroll
    for (int c = 0; c < 2; ++c){
      const int q0 = ((w << 1) | c) << 6;
      const int q  = q0 | lane;
      stage_sw(A,  arow, K, kt, q, As + q0 * 8);
      stage_sw(Bt, brow, K, kt, q, Bs + q0 * 8);
    }
    __syncthreads();
    bf16x8 af[4], bfr[4];
    #pragma unroll
    for (int i = 0; i < 4; ++i)
      af[i] = lds_frag(As, wr * 64 + i * 16 + l15, g);
    #pragma unroll
    for (int i = 0; i < 4; ++i)
      bfr[i] = lds_frag(Bs, wc * 64 + i * 16 + l15, g);
    #pragma unroll
    for (int mi = 0; mi < 4; ++mi)
      #pragma unroll
      for (int ni = 0; ni < 4; ++ni)
        acc[mi][ni] = mfma16(af[mi], bfr[ni], acc[mi][ni]);
  }
  const int row0 = bm * 128 + wr * 64, col0 = bn * 128 + wc * 64;
  #pragma unroll
  for (int mi = 0; mi < 4; ++mi){
    #pragma unroll
    for (int ni = 0; ni < 4; ++ni){
      #pragma unroll
      for (int r = 0; r < 4; ++r){
        const long ri = row0 + mi * 16 + g * 4 + r;
        const long ci = col0 + ni * 16 + l15;
        float v = acc[mi][ni][r];
        if (RES) v += Rs[ri * N + ci];
        if (OUT_BF16) ((u16*)C)[ri * N + ci] = f2bf(v);
        else          ((float*)C)[ri * N + ci] = v;
      }
    }
  }
}

// -------------------- GEMM 128x128 split-K: blockIdx.y = K-half, fp32 partials ----
__global__ __launch_bounds__(256) void k_gemmsk(const u16* __restrict__ A,
                                                const u16* __restrict__ Bt,
                                                float* __restrict__ P,
                                                int M, int N, int K, int nbn, int G){
  const int ks = blockIdx.y;
  const int KH = K >> 1;
  A  += (long)ks * KH;                      // row stride stays K
  Bt += (long)ks * KH;
  P  += (long)ks * M * N;
  int bm, bn;
  map_bmn(blockIdx.x, gridDim.x, nbn, G, bm, bn);
  const int t = threadIdx.x;
  const int w = t >> 6, lane = t & 63, l15 = lane & 15, g = lane >> 4;
  const int wr = w >> 1, wc = w & 1;
  __shared__ u16 As[4096];
  __shared__ u16 Bs[4096];
  f32x4 acc[4][4] = {};
  const long arow = (long)bm * 128;
  const long brow = (long)bn * 128;
  for (int kt = 0; kt < KH; kt += 32){
    __syncthreads();
    #pragma unroll
    for (int c = 0; c < 2; ++c){
      const int q0 = ((w << 1) | c) << 6;
      const int q  = q0 | lane;
      stage_sw(A,  arow, K, kt, q, As + q0 * 8);
      stage_sw(Bt, brow, K, kt, q, Bs + q0 * 8);
    }
    __syncthreads();
    bf16x8 af[4], bfr[4];
    #pragma unroll
    for (int i = 0; i < 4; ++i)
      af[i] = lds_frag(As, wr * 64 + i * 16 + l15, g);
    #pragma unroll
    for (int i = 0; i < 4; ++i)
      bfr[i] = lds_frag(Bs, wc * 64 + i * 16 + l15, g);
    #pragma unroll
    for (int mi = 0; mi < 4; ++mi)
      #pragma unroll
      for (int ni = 0; ni < 4; ++ni)
        acc[mi][ni] = mfma16(af[mi], bfr[ni], acc[mi][ni]);
  }
  const int row0 = bm * 128 + wr * 64, col0 = bn * 128 + wc * 64;
  #pragma unroll
  for (int mi = 0; mi < 4; ++mi){
    #pragma unroll
    for (int ni = 0; ni < 4; ++ni){
      #pragma unroll
      for (int r = 0; r < 4; ++r){
        const long ri = row0 + mi * 16 + g * 4 + r;
        const long ci = col0 + ni * 16 + l15;
        P[ri * N + ci] = acc[mi][ni][r];
      }
    }
  }
}

// -------------------- reduce 2 partials + residual: x += p0 + p1 -----------------
__global__ void k_red2(float* __restrict__ x, const float* __restrict__ p0,
                       const float* __restrict__ p1){
  const long i = ((long)blockIdx.x * 256 + threadIdx.x) * 4;
  const float4 a = *(const float4*)(p0 + i);
  const float4 b = *(const float4*)(p1 + i);
  float4 c = *(const float4*)(x + i);
  c.x += a.x + b.x; c.y += a.y + b.y; c.z += a.z + b.z; c.w += a.w + b.w;
  *(float4*)(x + i) = c;
}

// -------------------- GEMM 256x256, 8 waves, 4-deep, 2 phases/K-tile (R5-best) ----
template<int OUT_BF16>
__global__ __launch_bounds__(512, 2) void k_gemm256(const u16* __restrict__ A,
                                                    const u16* __restrict__ Bt,
                                                    void* C, int M, int N, int K){
  __shared__ u16 L[65536];                   // 128 KB: A slots [0,32768), B at +32768
  const int t = threadIdx.x;
  const int w = t >> 6, lane = t & 63, l15 = lane & 15, g = lane >> 4;
  const int wr = w >> 2, wc = w & 3;         // 2M x 4N waves; per-wave out 128x64
  const int nbm = M >> 8;
  int id = blockIdx.x;
  {
    const int cpx = gridDim.x >> 3;          // nwg % 8 == 0 at all call sites
    id = (id & 7) * cpx + (id >> 3);
  }
  const int bm = id % nbm, bn = id / nbm;
  const int NT = K >> 5;

  const int Rp0 = t >> 3;
  const int u0  = (t & 7) ^ (Rp0 & 7);
  const int R0  = (Rp0 << 1) | (u0 >> 2);
  const u16* pA0 = A  + ((long)bm * 256 + R0) * (long)K + ((u0 & 3) << 3);
  const u16* pB0 = Bt + ((long)bn * 256 + R0) * (long)K + ((u0 & 3) << 3);
  const u16* pA1 = pA0 + (long)128 * K;
  const u16* pB1 = pB0 + (long)128 * K;
  const int w0 = (t & ~63) * 8;              // wave-uniform LDS chunk base (u16)

  auto stageA = [&](int s){
    u16* d = L + s * 8192;
    GLOAD_LDS16(pA0, d + w0); GLOAD_LDS16(pA1, d + 4096 + w0);
    pA0 += 32; pA1 += 32;
  };
  auto stageB = [&](int s){
    u16* d = L + 32768 + s * 8192;
    GLOAD_LDS16(pB0, d + w0); GLOAD_LDS16(pB1, d + 4096 + w0);
    pB0 += 32; pB1 += 32;
  };

  stageA(0); stageB(0); stageA(1); stageB(1); stageA(2); stageB(2);
  asm volatile("s_waitcnt vmcnt(8)" ::: "memory");
  __builtin_amdgcn_s_barrier();

  f32x4 acc[8][4] = {};
  for (int tt = 0; tt < NT; ++tt){
    const u16* sA = L + (tt & 3) * 8192;
    const u16* sB = L + 32768 + (tt & 3) * 8192;
    // ---- phase 0: m-half 0 ----
    bf16x8 af0[4], bfr[4];
    #pragma unroll
    for (int j = 0; j < 4; ++j)
      af0[j] = lds_frag(sA, wr * 128 + j * 16 + l15, g);
    #pragma unroll
    for (int n = 0; n < 4; ++n)
      bfr[n] = lds_frag(sB, wc * 64 + n * 16 + l15, g);
    if (tt + 3 < NT) stageA((tt + 3) & 3);
    asm volatile("s_waitcnt lgkmcnt(0)" ::: "memory");
    __builtin_amdgcn_s_barrier();
    __builtin_amdgcn_s_setprio(1);
    #pragma unroll
    for (int mi = 0; mi < 4; ++mi)
      #pragma unroll
      for (int ni = 0; ni < 4; ++ni)
        acc[mi][ni] = mfma16(af0[mi], bfr[ni], acc[mi][ni]);
    __builtin_amdgcn_s_setprio(0);
    // ---- phase 1: m-half 1 ----
    bf16x8 af1[4];
    #pragma unroll
    for (int j = 0; j < 4; ++j)
      af1[j] = lds_frag(sA, wr * 128 + 64 + j * 16 + l15, g);
    if (tt + 3 < NT) stageB((tt + 3) & 3);
    asm volatile("s_waitcnt lgkmcnt(0)" ::: "memory");
    if (tt + 1 < NT){
      if (tt + 3 < NT)      asm volatile("s_waitcnt vmcnt(8)" ::: "memory");
      else if (tt + 2 < NT) asm volatile("s_waitcnt vmcnt(4)" ::: "memory");
      else                  asm volatile("s_waitcnt vmcnt(0)" ::: "memory");
    }
    __builtin_amdgcn_s_barrier();
    __builtin_amdgcn_s_setprio(1);
    #pragma unroll
    for (int mi = 0; mi < 4; ++mi)
      #pragma unroll
      for (int ni = 0; ni < 4; ++ni)
        acc[4 + mi][ni] = mfma16(af1[mi], bfr[ni], acc[4 + mi][ni]);
    __builtin_amdgcn_s_setprio(0);
  }
  const int row0 = bm * 256 + wr * 128, col0 = bn * 256 + wc * 64;
  #pragma unroll
  for (int mi = 0; mi < 8; ++mi){
    #pragma unroll
    for (int ni = 0; ni < 4; ++ni){
      #pragma unroll
      for (int r = 0; r < 4; ++r){
        const long ri = row0 + mi * 16 + g * 4 + r;
        const long ci = col0 + ni * 16 + l15;
        const float v = acc[mi][ni][r];
        if (OUT_BF16) ((u16*)C)[ri * N + ci] = f2bf(v);
        else          ((float*)C)[ri * N + ci] = v;
      }
    }
  }
}

// -------------------- RoPE in-place on bf16 qkv --------------------
__global__ void k_rope(u16* __restrict__ qkv){
  const int idx = blockIdx.x * 256 + threadIdx.x;   // S * 20 * 64
  const int i = idx & 63;
  const int head = (idx >> 6) % 20;
  const int s = idx / (64 * 20);
  const long base = (long)s * NQKV + (head < NHQ ? head * HDIM : DMODEL + (head - NHQ) * HDIM);
  u32* p = (u32*)(qkv + base + 2 * i);
  const u32 v = *p;
  const float x0 = bf2f((u16)(v & 0xffffu)), x1 = bf2f((u16)(v >> 16));
  const float ang = (float)s * exp2f(-0.29580575889569023f * (float)i);
  float sn, cs;
  sincosf(ang, &sn, &cs);
  const float y0 = x0 * cs - x1 * sn;
  const float y1 = x0 * sn + x1 * cs;
  *p = (u32)f2bf(y0) | ((u32)f2bf(y1) << 16);
}

// -------------------- Flash attention (causal, GQA), gload_lds staged ------------
__global__ __launch_bounds__(256) void k_attn(const u16* __restrict__ qkv,
                                              const u16* __restrict__ vT,
                                              u16* __restrict__ o){
  const int qb = blockIdx.x, h = blockIdx.y;
  const int kh = h >> 2;                      // GQA: G=4
  const int t = threadIdx.x, w = t >> 6, lane = t & 63, l15 = lane & 15, g = lane >> 4;
  __shared__ u16 Ks[2][8192];
  __shared__ u16 Vs[2][8192];
  __shared__ u16 Ps[4][16 * 72];
  const int q0 = qb * 64 + w * 16;
  bf16x8 aq[4];
  #pragma unroll
  for (int d0 = 0; d0 < 4; ++d0)
    aq[d0] = ld8(qkv + (long)(q0 + l15) * NQKV + h * HDIM + d0 * 32 + g * 8);
  f32x4 acc_o[8] = {};
  float mst[4], lst[4];
  #pragma unroll
  for (int r = 0; r < 4; ++r){ mst[r] = -1e30f; lst[r] = 0.f; }
  const float scale = 0.08838834764831843f;

  auto stageK = [&](int kt, int b){
    #pragma unroll
    for (int p = 0; p < 4; ++p){
      const int q = p * 256 + t;
      const int r = q >> 4, u = q & 15;
      const u16* gp = qkv + (long)(kt * 64 + r) * NQKV + DMODEL + kh * HDIM + ((u ^ (r & 15)) << 3);
      GLOAD_LDS16(gp, Ks[b] + (p * 256 + (t & ~63)) * 8);
    }
  };
  auto stageV = [&](int kt, int b){
    #pragma unroll
    for (int p = 0; p < 4; ++p){
      const int q = p * 256 + t;
      const int r = q >> 3, u = q & 7;
      const u16* gp = vT + ((long)kh * HDIM + r) * S_LEN + kt * 64 + ((u ^ (r & 7)) << 3);
      GLOAD_LDS16(gp, Vs[b] + (p * 256 + (t & ~63)) * 8);
    }
  };

  const int nkt = qb + 1;
  stageK(0, 0); stageV(0, 0);
  for (int kt = 0; kt < nkt; ++kt){
    const int kv0 = kt << 6;
    __builtin_amdgcn_s_barrier();            // (a) prev reads drained -> DMA may overwrite
    if (kt + 1 < nkt){
      stageK(kt + 1, (kt + 1) & 1);
      stageV(kt + 1, (kt + 1) & 1);
      asm volatile("s_waitcnt vmcnt(8)" ::: "memory");
    } else {
      asm volatile("s_waitcnt vmcnt(0)" ::: "memory");
    }
    __builtin_amdgcn_s_barrier();            // (b) tile kt globally visible
    const u16* K_ = Ks[kt & 1];
    const u16* V_ = Vs[kt & 1];
    // ---- S = Q K^T ----
    f32x4 sacc[4] = {};
    #pragma unroll
    for (int d0 = 0; d0 < 4; ++d0){
      #pragma unroll
      for (int j2 = 0; j2 < 4; ++j2){
        const bf16x8 bk = ld8(K_ + (j2 * 16 + l15) * 128 + ((((d0 << 2) | g) ^ l15) << 3));
        sacc[j2] = mfma16(aq[d0], bk, sacc[j2]);
      }
    }
    // ---- mask + online softmax (rows in 16-lane groups) ----
    float p[4][4], scl[4];
    #pragma unroll
    for (int r = 0; r < 4; ++r){
      const int qrow = q0 + g * 4 + r;
      float mx = -1e30f;
      #pragma unroll
      for (int j2 = 0; j2 < 4; ++j2){
        float sv = sacc[j2][r] * scale;
        sv = (kv0 + j2 * 16 + l15 <= qrow) ? sv : -1e30f;
        p[j2][r] = sv;
        mx = fmaxf(mx, sv);
      }
      #pragma unroll
      for (int off = 1; off < 16; off <<= 1) mx = fmaxf(mx, __shfl_xor(mx, off, 64));
      const float mnew = fmaxf(mst[r], mx);
      scl[r] = __expf(mst[r] - mnew);
      float rs = 0.f;
      #pragma unroll
      for (int j2 = 0; j2 < 4; ++j2){ p[j2][r] = __expf(p[j2][r] - mnew); rs += p[j2][r]; }
      #pragma unroll
      for (int off = 1; off < 16; off <<= 1) rs += __shfl_xor(rs, off, 64);
      lst[r] = lst[r] * scl[r] + rs;
      mst[r] = mnew;
    }
    #pragma unroll
    for (int n = 0; n < 8; ++n)
      #pragma unroll
      for (int r = 0; r < 4; ++r)
        acc_o[n][r] *= scl[r];
    // ---- P -> LDS (per-wave), then PV ----
    #pragma unroll
    for (int j2 = 0; j2 < 4; ++j2)
      #pragma unroll
      for (int r = 0; r < 4; ++r)
        Ps[w][(g * 4 + r) * 72 + j2 * 16 + l15] = f2bf(p[j2][r]);
    #pragma unroll
    for (int kk = 0; kk < 2; ++kk){
      const bf16x8 pa = ld8(Ps[w] + l15 * 72 + kk * 32 + g * 8);
      #pragma unroll
      for (int n = 0; n < 8; ++n){
        const int row = n * 16 + l15;
        const bf16x8 bv = ld8(V_ + row * 64 + ((((kk << 2) | g) ^ (l15 & 7)) << 3));
        acc_o[n] = mfma16(pa, bv, acc_o[n]);
      }
    }
    asm volatile("s_waitcnt lgkmcnt(0)" ::: "memory");   // drain my LDS reads (WAR)
  }
  #pragma unroll
  for (int n = 0; n < 8; ++n){
    #pragma unroll
    for (int r = 0; r < 4; ++r){
      const float ov = acc_o[n][r] / lst[r];
      o[(long)(q0 + g * 4 + r) * DMODEL + h * HDIM + n * 16 + l15] = f2bf(ov);
    }
  }
}

// -------------------- SwiGLU: silu(gate)*up --------------------
__global__ void k_swiglu(const u16* __restrict__ gu, u16* __restrict__ out){
  const long idx = ((long)blockIdx.x * 256 + threadIdx.x) * 8;
  const long s = idx >> 13;
  const int j = (int)(idx & 8191);
  const u16* gp = gu + s * 16384 + j;
  const uint4 gv = *(const uint4*)gp;
  const uint4 uv = *(const uint4*)(gp + PDIM);
  const u32 gw[4] = {gv.x, gv.y, gv.z, gv.w};
  const u32 uw[4] = {uv.x, uv.y, uv.z, uv.w};
  u32 ow[4];
  #pragma unroll
  for (int k = 0; k < 4; ++k){
    const float g0 = bf2f((u16)(gw[k] & 0xffffu)), g1 = bf2f((u16)(gw[k] >> 16));
    const float u0 = bf2f((u16)(uw[k] & 0xffffu)), u1 = bf2f((u16)(uw[k] >> 16));
    const float s0 = g0 / (1.f + __expf(-g0)) * u0;
    const float s1 = g1 / (1.f + __expf(-g1)) * u1;
    ow[k] = (u32)f2bf(s0) | ((u32)f2bf(s1) << 16);
  }
  uint4 ro; ro.x = ow[0]; ro.y = ow[1]; ro.z = ow[2]; ro.w = ow[3];
  *(uint4*)(out + idx) = ro;
}

// -------------------- launch --------------------
extern "C" void kernel_launch(void* const* d_in, const int* in_sizes, int n_in,
                              void* d_out, int out_size, void* d_ws, size_t ws_size,
                              hipStream_t stream){
  const int*   tokens       = (const int*)d_in[0];
  const float* embed        = (const float*)d_in[1];
  const float* attn_norm_w  = (const float*)d_in[2];
  const float* qkv_w        = (const float*)d_in[3];
  const float* attn_out_w   = (const float*)d_in[4];
  const float* mlp_norm_w   = (const float*)d_in[5];
  const float* mlp_in_w     = (const float*)d_in[6];
  const float* mlp_out_w    = (const float*)d_in[7];
  const float* final_norm_w = (const float*)d_in[8];
  const float* lm_head_w    = (const float*)d_in[9];

  char* ws = (char*)d_ws;
  float* xf  = (float*)(ws);                    // 16.78 MB residual (fp32)
  u16* hbf   = (u16*)(ws + 16777216);           //  8.39 MB normed activations
  u16* qkvb  = (u16*)(ws + 25165824);           // 12.58 MB qkv
  u16* obf   = (u16*)(ws + 37748736);           //  8.39 MB attn out
  u16* gub   = (u16*)(ws + 46137344);           // 67.11 MB gate|up (reused as fp32 partials for mlp_out)
  u16* hb2   = (u16*)(ws + 113246208);          // 33.55 MB silu(g)*u
  u16* wbuf  = (u16*)(ws + 146800640);          // 131.07 MB transposed bf16 weights
  u16* vTb   = (u16*)(ws + 277872640);          //  2.10 MB transposed V
  float* pp  = (float*)gub;                     // 33.55 MB: 2 x [2048x2048] fp32 partials

  k_embed<<<S_LEN, 256, 0, stream>>>(tokens, embed, xf);
  for (int l = 0; l < 2; ++l){
    k_rmsnorm<<<S_LEN, 256, 0, stream>>>(xf, attn_norm_w + (long)l * DMODEL, hbf);
    k_convT<<<dim3(NQKV/64, DMODEL/64), 256, 0, stream>>>(
        qkv_w + (long)l * DMODEL * NQKV, wbuf, NQKV, DMODEL);
    k_gemm<1,0><<<(S_LEN/128) * (NQKV/128), 256, 0, stream>>>(
        hbf, wbuf, qkvb, nullptr, S_LEN, NQKV, DMODEL, NQKV/128, 4);
    k_rope<<<(S_LEN * 20 * 64) / 256, 256, 0, stream>>>(qkvb);
    k_transV<<<dim3(S_LEN/64, 2, 4), 256, 0, stream>>>(qkvb, vTb);
    k_attn<<<dim3(S_LEN/64, NHQ), 256, 0, stream>>>(qkvb, vTb, obf);
    k_convT<<<dim3(DMODEL/64, DMODEL/64), 256, 0, stream>>>(
        attn_out_w + (long)l * DMODEL * DMODEL, wbuf, DMODEL, DMODEL);
    k_gemm<0,1><<<(S_LEN/128) * (DMODEL/128), 256, 0, stream>>>(
        obf, wbuf, xf, xf, S_LEN, DMODEL, DMODEL, DMODEL/128, 4);
    k_rmsnorm<<<S_LEN, 256, 0, stream>>>(xf, mlp_norm_w + (long)l * DMODEL, hbf);
    k_convT<<<dim3((2*PDIM)/64, DMODEL/64), 256, 0, stream>>>(
        mlp_in_w + (long)l * DMODEL * 2 * PDIM, wbuf, 2*PDIM, DMODEL);
    k_gemm256<1><<<(S_LEN/256) * ((2*PDIM)/256), 512, 0, stream>>>(
        hbf, wbuf, gub, S_LEN, 2*PDIM, DMODEL);
    k_swiglu<<<(S_LEN * PDIM / 8) / 256, 256, 0, stream>>>(gub, hb2);
    k_convT<<<dim3(DMODEL/64, PDIM/64), 256, 0, stream>>>(
        mlp_out_w + (long)l * PDIM * DMODEL, wbuf, DMODEL, PDIM);
    k_gemmsk<<<dim3((S_LEN/128) * (DMODEL/128), 2), 256, 0, stream>>>(
        hb2, wbuf, pp, S_LEN, DMODEL, PDIM, DMODEL/128, 2);
    k_red2<<<(S_LEN * DMODEL) / 1024, 256, 0, stream>>>(
        xf, pp, pp + (long)S_LEN * DMODEL);
  }
  k_rmsnorm<<<S_LEN, 256, 0, stream>>>(xf, final_norm_w, hbf);
  k_convT<<<dim3(VOCAB/64, DMODEL/64), 256, 0, stream>>>(lm_head_w, wbuf, VOCAB, DMODEL);
  k_gemm256<0><<<(S_LEN/256) * (VOCAB/256), 512, 0, stream>>>(
      hbf, wbuf, (float*)d_out, S_LEN, VOCAB, DMODEL);
}